// Round 3
// baseline (254.343 us; speedup 1.0000x reference)
//
#include <hip/hip_runtime.h>
#include <math.h>

#define NCODE 64
#define SIGMA 10.0f
#define LOG2E 1.4426950408889634f
#define PPT 2          // points per thread (round 3: 4->2, grid 1024->2048 for 100% occupancy cap)
#define BLK 256

// Straight-line kernel: each thread owns exactly PPT points (grid covers npts).
// Pass 1: bit-exact (vs numpy) distance/logit -> max + argmax.
// Pass 2a: fast log2-domain softmax denominator.
// Pass 2b: per-bin normalized contribution -> rotated LDS atomicAdd.
// Constant-indexed loops everywhere: NO dynamically-indexed register arrays
// (round-1 profiling showed those force scratch spills, 158 B/point).
// Round-3 change: PPT 4->2 so the grid is 2048 blocks = 8 blocks/CU =
// 32 waves/CU (the HW cap) — round 2 showed latency-bound at 33% occupancy.
__global__ __launch_bounds__(BLK) void vq_kernel(
    const float* __restrict__ x,
    const float* __restrict__ embed,
    float* __restrict__ out_q,          // [npts*2] fp32
    float* __restrict__ out_lik,        // [64] fp32, pre-zeroed
    int npts)
{
    __shared__ float4 scode[NCODE];     // (e0, e1, ||e||^2_np, 0)  exact
    __shared__ float4 sfast[NCODE];     // (20*log2e*e0, 20*log2e*e1, -10*log2e*n, 0)
    __shared__ float  slik[NCODE];

    const int t = threadIdx.x;
    if (t < NCODE) {
        float e0 = embed[2 * t];
        float e1 = embed[2 * t + 1];
        // n_j exactly as np: rn(rn(e0*e0) + rn(e1*e1))
        float n = __fadd_rn(__fmul_rn(e0, e0), __fmul_rn(e1, e1));
        scode[t] = make_float4(e0, e1, n, 0.0f);
        const float k20 = 20.0f * LOG2E;
        const float km10 = -10.0f * LOG2E;
        sfast[t] = make_float4(k20 * e0, k20 * e1, km10 * n, 0.0f);
        slik[t] = 0.0f;
    }
    __syncthreads();

    const int gid    = blockIdx.x * BLK + t;
    const int stride = gridDim.x * BLK;          // 524288 for the 1M-point shape
    const float2* __restrict__ xp = (const float2*)x;
    float2* __restrict__ qp = (float2*)out_q;

    // ---- load my PPT points (coalesced: stride-separated full-wave rows) ----
    float2 p[PPT];
    float  s[PPT];
    int    idx[PPT];
#pragma unroll
    for (int k = 0; k < PPT; ++k) {
        idx[k] = gid + k * stride;
        p[k] = xp[idx[k]];
        // s exactly as np: rn(rn(p0*p0) + rn(p1*p1))
        s[k] = __fadd_rn(__fmul_rn(p[k].x, p[k].x), __fmul_rn(p[k].y, p[k].y));
    }

    // ---- pass 1: bit-exact logits, max + argmax (first-occurrence ties) ----
    float m[PPT];
    int   best[PPT];
#pragma unroll
    for (int k = 0; k < PPT; ++k) { m[k] = -INFINITY; best[k] = 0; }

#pragma unroll 8
    for (int j = 0; j < NCODE; ++j) {
        float4 c = scode[j];
#pragma unroll
        for (int k = 0; k < PPT; ++k) {
            // np sgemm model (OpenBLAS K=2): dot = fma(p1,e1, rn(p0*e0))
            float dot = fmaf(p[k].y, c.y, __fmul_rn(p[k].x, c.x));
            // rn(s - 2*dot): 2*dot is exact, fma(-2,dot,s) rounds once == fsub
            float d = __fadd_rn(fmaf(-2.0f, dot, s[k]), c.z);
            float l = __fmul_rn(-SIGMA, d);
            if (l > m[k]) { m[k] = l; best[k] = j; }
        }
    }

    // ---- straight-through forward value: hard_q = embed[argmax] ----
#pragma unroll
    for (int k = 0; k < PPT; ++k) {
        float4 cb = scode[best[k]];
        qp[idx[k]] = make_float2(cb.x, cb.y);
    }

    // ---- pass 2a: softmax denominator (fast path; only feeds the 1M-mean) ----
    // g_j = log2e*(logit_j + 10*s)  computed as  A_j*p0 + B_j*p1 + C_j
    float gref[PPT], ssum[PPT];
#pragma unroll
    for (int k = 0; k < PPT; ++k) {
        gref[k] = __fmul_rn(fmaf(10.0f, s[k], m[k]), LOG2E);
        ssum[k] = 0.0f;
    }
#pragma unroll 8
    for (int j = 0; j < NCODE; ++j) {
        float4 f = sfast[j];
#pragma unroll
        for (int k = 0; k < PPT; ++k) {
            float g = fmaf(p[k].x, f.x, fmaf(p[k].y, f.y, f.z));
            ssum[k] += __builtin_amdgcn_exp2f(g - gref[k]);
        }
    }
    // fold normalization into the exponent: exp2(g - gref - log2(ssum))
#pragma unroll
    for (int k = 0; k < PPT; ++k)
        gref[k] += __builtin_amdgcn_logf(ssum[k]);   // v_log_f32 = log2

    // ---- pass 2b: per-bin contributions, rotated so each wave-instr's 64
    // LDS atomics hit 64 distinct addresses (2-way bank alias only) ----
#pragma unroll 8
    for (int r = 0; r < NCODE; ++r) {
        int bin = (r + t) & (NCODE - 1);
        float4 f = sfast[bin];
        float tt = 0.0f;
#pragma unroll
        for (int k = 0; k < PPT; ++k) {
            float g = fmaf(p[k].x, f.x, fmaf(p[k].y, f.y, f.z));
            tt += __builtin_amdgcn_exp2f(g - gref[k]);
        }
        atomicAdd(&slik[bin], tt);
    }

    __syncthreads();
    if (t < NCODE) {
        atomicAdd(&out_lik[t], slik[t] * (1.0f / 1048576.0f));
    }
}

extern "C" void kernel_launch(void* const* d_in, const int* in_sizes, int n_in,
                              void* d_out, int out_size, void* d_ws, size_t ws_size,
                              hipStream_t stream) {
    (void)n_in; (void)d_ws; (void)ws_size;
    const float* x     = (const float*)d_in[0];   // [64*32*32*32] fp32
    const float* embed = (const float*)d_in[1];   // [64*2] fp32

    const int npts = in_sizes[0] / 2;             // 1,048,576 points
    float* out_q   = (float*)d_out;               // [npts*2]
    float* out_lik = (float*)d_out + (out_size - NCODE); // [64] tail

    // likelihood accumulators must start at 0 (harness poisons d_out with 0xAA)
    hipMemsetAsync(out_lik, 0, NCODE * sizeof(float), stream);

    const int nblocks = npts / (BLK * PPT);       // 2048: exact cover, 8 blocks/CU
    vq_kernel<<<nblocks, BLK, 0, stream>>>(x, embed, out_q, out_lik, npts);
}

// Round 4
// 97.488 us; speedup vs baseline: 2.6090x; 2.6090x over previous
//
#include <hip/hip_runtime.h>
#include <math.h>

#define NCODE 64
#define SIGMA 10.0f
#define LOG2E 1.4426950408889634f
#define PPT 4          // points per thread; grid = npts/(BLK*PPT) = 1024 = 4 blocks/CU
#define BLK 256

// Round-4 structure (round-3 post-mortem: LDS-atomic + tail-atomic bound, not VALU):
//  - acc[64] in REGISTERS, constant-indexed only (fully unrolled pass 2b).
//  - block reduction: compacted butterfly (63 shuffles) -> lane l owns bin l,
//    cross-wave combine through 1KB LDS, coalesced partial write to d_ws.
//  - no atomics anywhere; stage-2 kernel reduces the 1024x64 partials.
__global__ __launch_bounds__(BLK, 4) void vq_main(
    const float* __restrict__ x,
    const float* __restrict__ embed,
    float* __restrict__ out_q,          // [npts*2] fp32
    float* __restrict__ partial)        // [nblk*64] fp32 (d_ws)
{
    __shared__ float4 scode[NCODE];     // (e0, e1, ||e||^2_np, 0)  exact
    __shared__ float4 sfast[NCODE];     // (20*log2e*e0, 20*log2e*e1, -10*log2e*n, 0)
    __shared__ float  sred[BLK / 64][NCODE];

    const int t = threadIdx.x;
    if (t < NCODE) {
        float e0 = embed[2 * t];
        float e1 = embed[2 * t + 1];
        // n_j exactly as np: rn(rn(e0*e0) + rn(e1*e1))
        float n = __fadd_rn(__fmul_rn(e0, e0), __fmul_rn(e1, e1));
        scode[t] = make_float4(e0, e1, n, 0.0f);
        const float k20  = 20.0f * LOG2E;
        const float km10 = -10.0f * LOG2E;
        sfast[t] = make_float4(k20 * e0, k20 * e1, km10 * n, 0.0f);
    }
    __syncthreads();

    const int gid    = blockIdx.x * BLK + t;
    const int stride = gridDim.x * BLK;          // 262144
    const float2* __restrict__ xp = (const float2*)x;
    float2* __restrict__ qp = (float2*)out_q;

    // ---- load my PPT points (coalesced full-wave rows) ----
    float2 p[PPT];
    float  s[PPT];
    int    idx[PPT];
#pragma unroll
    for (int k = 0; k < PPT; ++k) {
        idx[k] = gid + k * stride;
        p[k] = xp[idx[k]];
        // s exactly as np: rn(rn(p0*p0) + rn(p1*p1))
        s[k] = __fadd_rn(__fmul_rn(p[k].x, p[k].x), __fmul_rn(p[k].y, p[k].y));
    }

    // ---- pass 1: bit-exact logits, max + argmax (first-occurrence ties) ----
    float m[PPT];
    int   best[PPT];
#pragma unroll
    for (int k = 0; k < PPT; ++k) { m[k] = -INFINITY; best[k] = 0; }

#pragma unroll 8
    for (int j = 0; j < NCODE; ++j) {
        float4 c = scode[j];
#pragma unroll
        for (int k = 0; k < PPT; ++k) {
            // np sgemm model (OpenBLAS K=2): dot = fma(p1,e1, rn(p0*e0))
            float dot = fmaf(p[k].y, c.y, __fmul_rn(p[k].x, c.x));
            float d = __fadd_rn(fmaf(-2.0f, dot, s[k]), c.z);
            float l = __fmul_rn(-SIGMA, d);
            if (l > m[k]) { m[k] = l; best[k] = j; }
        }
    }

    // ---- straight-through forward value: hard_q = embed[argmax] ----
#pragma unroll
    for (int k = 0; k < PPT; ++k) {
        float4 cb = scode[best[k]];
        qp[idx[k]] = make_float2(cb.x, cb.y);
    }

    // ---- pass 2a: softmax denominator (fast log2-domain path) ----
    float gref[PPT], ssum[PPT];
#pragma unroll
    for (int k = 0; k < PPT; ++k) {
        gref[k] = __fmul_rn(fmaf(10.0f, s[k], m[k]), LOG2E);
        ssum[k] = 0.0f;
    }
#pragma unroll 8
    for (int j = 0; j < NCODE; ++j) {
        float4 f = sfast[j];
#pragma unroll
        for (int k = 0; k < PPT; ++k) {
            float g = fmaf(p[k].x, f.x, fmaf(p[k].y, f.y, f.z));
            ssum[k] += __builtin_amdgcn_exp2f(g - gref[k]);
        }
    }
    // fold 1/ssum into the exponent: exp2(g - gref - log2(ssum))
#pragma unroll
    for (int k = 0; k < PPT; ++k)
        gref[k] += __builtin_amdgcn_logf(ssum[k]);   // v_log_f32 = log2

    // ---- pass 2b: normalized contributions -> register acc (constant idx) ----
    float acc[NCODE];
#pragma unroll
    for (int j = 0; j < NCODE; ++j) acc[j] = 0.0f;

#pragma unroll
    for (int j = 0; j < NCODE; ++j) {
        float4 f = sfast[j];
        float tt = 0.0f;
#pragma unroll
        for (int k = 0; k < PPT; ++k) {
            float g = fmaf(p[k].x, f.x, fmaf(p[k].y, f.y, f.z));
            tt += __builtin_amdgcn_exp2f(g - gref[k]);
        }
        acc[j] = tt;
    }

    // ---- compacted butterfly: 63 shuffles; lane l ends owning wave-sum of bin l ----
    const int lane = t & 63;
#pragma unroll
    for (int step = 32; step >= 1; step >>= 1) {
        const bool upper = (lane & step) != 0;
#pragma unroll
        for (int i = 0; i < step; ++i) {
            float lo = acc[i], hi = acc[i + step];
            float send = upper ? lo : hi;
            float keep = upper ? hi : lo;
            acc[i] = keep + __shfl_xor(send, step, 64);
        }
    }

    // ---- cross-wave combine + coalesced partial write ----
    const int wv = t >> 6;
    sred[wv][lane] = acc[0];
    __syncthreads();
    if (t < NCODE) {
        float tot = sred[0][t] + sred[1][t] + sred[2][t] + sred[3][t];
        partial[blockIdx.x * NCODE + t] = tot;
    }
}

// Stage 2: reduce nblk x 64 partials -> out_lik (no atomics, deterministic).
__global__ __launch_bounds__(256) void vq_reduce(
    const float* __restrict__ partial,
    float* __restrict__ out_lik,
    int nblk, float scale)
{
    __shared__ float sm[4];
    const int b = blockIdx.x;       // bin
    const int t = threadIdx.x;
    float s = 0.0f;
    for (int i = t; i < nblk; i += 256)
        s += partial[i * NCODE + b];
#pragma unroll
    for (int msk = 32; msk >= 1; msk >>= 1)
        s += __shfl_xor(s, msk, 64);
    if ((t & 63) == 0) sm[t >> 6] = s;
    __syncthreads();
    if (t == 0)
        out_lik[b] = (sm[0] + sm[1] + sm[2] + sm[3]) * scale;
}

extern "C" void kernel_launch(void* const* d_in, const int* in_sizes, int n_in,
                              void* d_out, int out_size, void* d_ws, size_t ws_size,
                              hipStream_t stream) {
    (void)n_in; (void)ws_size;
    const float* x     = (const float*)d_in[0];   // [64*32*32*32] fp32
    const float* embed = (const float*)d_in[1];   // [64*2] fp32

    const int npts = in_sizes[0] / 2;             // 1,048,576 points
    float* out_q   = (float*)d_out;               // [npts*2]
    float* out_lik = (float*)d_out + (out_size - NCODE); // [64] tail
    float* partial = (float*)d_ws;                // [nblk*64] scratch

    const int nblk = npts / (BLK * PPT);          // 1024
    vq_main<<<nblk, BLK, 0, stream>>>(x, embed, out_q, partial);
    vq_reduce<<<NCODE, 256, 0, stream>>>(partial, out_lik, nblk,
                                         1.0f / (float)npts);
}